// Round 5
// baseline (491.824 us; speedup 1.0000x reference)
//
#include <hip/hip_runtime.h>
#include <math.h>

#define BATCH 512
#define SEQ   200
#define TOK   10
#define EMB   25
#define XPAD  28    // xs row stride (floats): 112 B, 16B-aligned rows
#define HID   64
#define G3    192   // 3*HID

__device__ __forceinline__ float fast_sigmoid(float t) {
    float e = __expf(-t);
    return __builtin_amdgcn_rcpf(1.f + e);
}
__device__ __forceinline__ float fast_tanh(float t) {
    float e2 = __expf(2.f * t);
    return 1.f - 2.f * __builtin_amdgcn_rcpf(e2 + 1.f);
}

// Barrier that orders LDS producer->consumer WITHOUT draining vmcnt:
// writer-side ds ops complete (lgkmcnt(0)), then s_barrier. The global
// out-store stays fire-and-forget (no vmcnt(0) on the critical path).
#define LDS_BARRIER() do {                                   \
    asm volatile("s_waitcnt lgkmcnt(0)" ::: "memory");       \
    __builtin_amdgcn_s_barrier();                            \
    asm volatile("" ::: "memory");                           \
} while (0)

// ---------------------------------------------------------------------------
// Kernel 1: masked-mean embedding bag + step mask (unchanged)
// ---------------------------------------------------------------------------
__global__ __launch_bounds__(256) void emb_mean_kernel(
    const int* __restrict__ ids_g, const float* __restrict__ emb,
    float* __restrict__ x, float* __restrict__ mask)
{
    int grp  = blockIdx.x * 8 + (threadIdx.x >> 5);
    int lane = threadIdx.x & 31;
    if (grp >= BATCH * SEQ) return;
    const int* ids = ids_g + (size_t)grp * TOK;
    float acc = 0.f;
    int cnt = 0;
    #pragma unroll
    for (int t = 0; t < TOK; t++) {
        int id = ids[t];
        if (id != 0) {
            cnt++;
            if (lane < EMB) acc += emb[(size_t)id * EMB + lane];
        }
    }
    if (lane < EMB)
        x[(size_t)grp * EMB + lane] = cnt ? acc / (float)cnt : 0.f;
    if (lane == 0)
        mask[grp] = (ids[0] != 0) ? 1.f : 0.f;
}

// ---------------------------------------------------------------------------
// Kernel 2: GRU scan — SIX waves per (b,dir): wave = (gate g, k-half kh).
// Round 2/4 post-mortem: the scheduler SINKS loop-invariant weight loads
// back into the loop whenever demand exceeds its 64-reg occupancy target
// (FETCH stays flat = L1 reloads, ~273 KB/step/CU = the 205us wall);
// pinning without budget (round 3) trades that for scratch spills
// (FETCH 9.5MB). Fix: engineer per-lane demand UNDER the 64-reg tier:
//   32 U-regs (k-half) + 13 W-regs (e-half) + ~15 temps ~= 60.
// Pins now just forbid re-sinking; nothing needs to spill. Biases live in
// LDS (combiner adds them). 2 lgkm-only barriers/step; store stays
// fire-and-forget; x-proj for step+1 fills the combine window.
//   w: 0=z0 1=z1 2=r0 3=r1 4=h0(+combine) 5=h1
// ---------------------------------------------------------------------------

#define U32_LIST(M) \
  M(0)  M(1)  M(2)  M(3)  M(4)  M(5)  M(6)  M(7)  \
  M(8)  M(9)  M(10) M(11) M(12) M(13) M(14) M(15) \
  M(16) M(17) M(18) M(19) M(20) M(21) M(22) M(23) \
  M(24) M(25) M(26) M(27) M(28) M(29) M(30) M(31)

#define W13_LIST(M) \
  M(0) M(1) M(2) M(3) M(4) M(5) M(6) M(7) M(8) M(9) M(10) M(11) M(12)

#define DECL_U(t) float u##t = U[(size_t)(kstart + (t)) * G3 + col];
#define DECL_W(t) float w##t = ((t) < ne) ? W[(size_t)(estart + (t)) * G3 + col] : 0.f;
#define PIN_U(t)  asm volatile("" : "+v"(u##t));
#define PIN_W(t)  asm volatile("" : "+v"(w##t));

// one float4 broadcast read of this wave's hs half, 4 fmas (2 accumulators)
#define RECQ(q, i0, i1, i2, i3) {                 \
    const float4 hv = hs4[q];                     \
    a0 = fmaf(hv.x, u##i0, a0);                   \
    a1 = fmaf(hv.y, u##i1, a1);                   \
    a0 = fmaf(hv.z, u##i2, a0);                   \
    a1 = fmaf(hv.w, u##i3, a1); }

#define XQ(q, i0, i1, i2, i3) {                   \
    const float4 xv = xr4[q];                     \
    p0 = fmaf(xv.x, w##i0, p0);                   \
    p1 = fmaf(xv.y, w##i1, p1);                   \
    p0 = fmaf(xv.z, w##i2, p0);                   \
    p1 = fmaf(xv.w, w##i3, p1); }

// x-projection over this wave's e-half: rows are 16B-aligned, estart is
// 0 or 12 (both float4-aligned); reads never exceed e=24.
#define XPROJ(P, XR) do {                                  \
    const float4* xr4 = (const float4*)((XR) + estart);    \
    float p0 = 0.f, p1 = 0.f;                              \
    XQ(0, 0, 1, 2, 3)  XQ(1, 4, 5, 6, 7)  XQ(2, 8, 9, 10, 11) \
    p0 = fmaf((XR)[estart + 12], w12, p0);                 \
    P = p0 + p1;                                           \
} while (0)

__global__ __launch_bounds__(384)
__attribute__((amdgpu_waves_per_eu(6, 6)))
void gru_kernel(
    const float* __restrict__ xg, const float* __restrict__ maskg,
    const float* __restrict__ W_f, const float* __restrict__ U_f, const float* __restrict__ b_f,
    const float* __restrict__ W_b, const float* __restrict__ U_b, const float* __restrict__ b_b,
    float* __restrict__ outg, float* __restrict__ hT)
{
    const int bidx = blockIdx.x;
    const int dir  = bidx >> 9;        // 0 = forward, 1 = backward
    const int b    = bidx & 511;
    const int tid  = threadIdx.x;
    const int w    = tid >> 6;         // wave 0..5
    const int j    = tid & 63;         // hidden column
    const int g    = w >> 1;           // gate: 0=z 1=r 2=h
    const int kh   = w & 1;            // k/e half

    const float* W    = dir ? W_b : W_f;
    const float* U    = dir ? U_b : U_f;
    const float* bias = dir ? b_b : b_f;

    const int col    = g * HID + j;
    const int kstart = kh * 32;        // U k-range [kstart, kstart+32)
    const int estart = kh * 12;        // W e-range [estart, estart+ne)
    const int ne     = 12 + kh;        // 12 (+ zero pad w12) or 13

    __shared__ __align__(16) float xs[SEQ * XPAD];   // 22.4 KB, padded rows
    __shared__ float ms[SEQ];
    __shared__ __align__(16) float hs[HID];
    __shared__ float chan[8][HID];     // z0 z1 r0 r1 hx0 hx1 hr0 hr1
    __shared__ float bZs[HID], bRs[HID], bHXs[HID], bHRs[HID];

    // cooperative staging (coalesced global reads, padded LDS rows)
    for (int i = tid; i < SEQ * EMB; i += 384) {
        int s_ = i / EMB;
        int e_ = i - s_ * EMB;
        xs[s_ * XPAD + e_] = xg[(size_t)b * (SEQ * EMB) + i];
    }
    for (int i = tid; i < SEQ; i += 384) ms[i] = maskg[(size_t)b * SEQ + i];
    if (tid < HID) {
        hs[tid]   = 0.f;
        bZs[tid]  = bias[tid] + bias[G3 + tid];
        bRs[tid]  = bias[HID + tid] + bias[G3 + HID + tid];
        bHXs[tid] = bias[2 * HID + tid];
        bHRs[tid] = bias[G3 + 2 * HID + tid];
    }

    // per-lane weight slices (named scalars, pinned: demand fits the budget,
    // pins only forbid the scheduler from re-sinking the loads)
    U32_LIST(DECL_U)
    W13_LIST(DECL_W)
    U32_LIST(PIN_U)
    W13_LIST(PIN_W)

    __syncthreads();   // staging barrier (vmcnt drain fine, once)

    const float4* hs4 = (const float4*)(hs + kstart);
    const int sdelta = dir ? -1 : 1;
    int s = dir ? (SEQ - 1) : 0;
    float h = 0.f;     // running hidden state (combiner wave 4 only)
    float* obase = outg + (size_t)b * SEQ * (2 * HID) + dir * HID + j;

    // software-pipelined x-projection for step 0
    float px;
    XPROJ(px, xs + s * XPAD);

    for (int step = 0; step < SEQ; step++) {
        // recurrent partial over this wave's k-half (broadcast b128 reads)
        float a0 = 0.f, a1 = 0.f;
        RECQ(0,  0,  1,  2,  3)   RECQ(1,  4,  5,  6,  7)
        RECQ(2,  8,  9, 10, 11)   RECQ(3, 12, 13, 14, 15)
        RECQ(4, 16, 17, 18, 19)   RECQ(5, 20, 21, 22, 23)
        RECQ(6, 24, 25, 26, 27)   RECQ(7, 28, 29, 30, 31)
        const float a = a0 + a1;

        if (g < 2) {
            chan[g * 2 + kh][j] = a + px;    // z/r: x-part and rec-part merge
        } else {
            chan[4 + kh][j] = px;            // h: keep split (hh=tanh(xh+r*rh))
            chan[6 + kh][j] = a;
        }

        LDS_BARRIER();   // A: all partials visible

        if (w == 4) {
            float z  = fast_sigmoid(chan[0][j] + chan[1][j] + bZs[j]);
            float r  = fast_sigmoid(chan[2][j] + chan[3][j] + bRs[j]);
            float XH = chan[4][j] + chan[5][j] + bHXs[j];
            float RH = chan[6][j] + chan[7][j] + bHRs[j];
            float hh = fast_tanh(XH + r * RH);
            float hn = z * h + (1.f - z) * hh;
            hn = (ms[s] != 0.f) ? hn : h;
            h = hn;
            hs[j] = hn;
            obase[(size_t)s * (2 * HID)] = hn;   // fire-and-forget
        }

        // x-projection for the NEXT step (h-independent): overlaps the
        // combiner's latency and the other waves' barrier wait.
        {
            const int sn = (step < SEQ - 1) ? s + sdelta : s;
            XPROJ(px, xs + sn * XPAD);
            s = sn;
        }

        LDS_BARRIER();   // B: new hs visible to all waves
    }
    if (w == 4 && dir == 0) hT[(size_t)b * HID + j] = h;
}

// ---------------------------------------------------------------------------
// Kernel 3: attention pooling (unchanged). One block (256 thr) per batch.
// ---------------------------------------------------------------------------
__global__ __launch_bounds__(256) void attn_kernel(
    const float* __restrict__ outg, const float* __restrict__ maskg,
    const float* __restrict__ hT,
    const float* __restrict__ W_k, const float* __restrict__ b_k,
    const float* __restrict__ W_q, const float* __restrict__ b_q,
    const float* __restrict__ W_e, const float* __restrict__ b_e,
    float* __restrict__ ctx)
{
    const int b   = blockIdx.x;
    const int tid = threadIdx.x;

    __shared__ float Wks[2 * HID * HID];   // 128x64 = 32 KB
    __shared__ float qs[HID];
    __shared__ float es[SEQ];

    for (int i = tid; i < 2 * HID * HID; i += 256) Wks[i] = W_k[i];
    if (tid < HID) {
        float q = b_q[tid];
        const float* hrow = hT + (size_t)b * HID;
        #pragma unroll 8
        for (int i = 0; i < HID; i++) q = fmaf(hrow[i], W_q[i * HID + tid], q);
        qs[tid] = q;
    }
    __syncthreads();

    const int wave = tid >> 6;
    const int lane = tid & 63;
    const float bk = b_k[lane];
    const float we = W_e[lane];
    const float be = b_e[0];

    // phase 1: scores e[s]; each wave takes every 4th s
    for (int s = wave; s < SEQ; s += 4) {
        const float* orow = outg + ((size_t)b * SEQ + s) * (2 * HID);
        float a0 = 0.f, a1 = 0.f, a2 = 0.f, a3 = 0.f;
        #pragma unroll
        for (int i = 0; i < 2 * HID; i += 4) {
            a0 = fmaf(orow[i + 0], Wks[(i + 0) * HID + lane], a0);
            a1 = fmaf(orow[i + 1], Wks[(i + 1) * HID + lane], a1);
            a2 = fmaf(orow[i + 2], Wks[(i + 2) * HID + lane], a2);
            a3 = fmaf(orow[i + 3], Wks[(i + 3) * HID + lane], a3);
        }
        float t = tanhf(((a0 + a1) + (a2 + a3)) + bk + qs[lane]) * we;
        #pragma unroll
        for (int off = 32; off > 0; off >>= 1) t += __shfl_down(t, off);
        if (lane == 0) {
            float pen = (maskg[(size_t)b * SEQ + s] != 0.f) ? 0.f : -1e9f;
            es[s] = t + be + pen;
        }
    }
    __syncthreads();

    // phase 2: softmax over the 200 scores (single wave)
    if (tid < 64) {
        float mx = -1e30f;
        for (int s2 = tid; s2 < SEQ; s2 += 64) mx = fmaxf(mx, es[s2]);
        #pragma unroll
        for (int off = 32; off > 0; off >>= 1) mx = fmaxf(mx, __shfl_xor(mx, off));
        float sum = 0.f;
        for (int s2 = tid; s2 < SEQ; s2 += 64) {
            float w = expf(es[s2] - mx);
            es[s2] = w;
            sum += w;
        }
        #pragma unroll
        for (int off = 32; off > 0; off >>= 1) sum += __shfl_xor(sum, off);
        float inv = 1.f / sum;
        for (int s2 = tid; s2 < SEQ; s2 += 64) es[s2] *= inv;
    }
    __syncthreads();

    // phase 3: context[j] = sum_s w[s] * out[b,s,j]
    if (tid < 2 * HID) {
        const int jj = tid;
        float a0 = 0.f, a1 = 0.f;
        for (int s2 = 0; s2 < SEQ; s2 += 2) {
            a0 = fmaf(es[s2],     outg[((size_t)b * SEQ + s2)     * (2 * HID) + jj], a0);
            a1 = fmaf(es[s2 + 1], outg[((size_t)b * SEQ + s2 + 1) * (2 * HID) + jj], a1);
        }
        ctx[(size_t)b * (2 * HID) + jj] = a0 + a1;
    }
}

// ---------------------------------------------------------------------------
extern "C" void kernel_launch(void* const* d_in, const int* in_sizes, int n_in,
                              void* d_out, int out_size, void* d_ws, size_t ws_size,
                              hipStream_t stream) {
    const int*   ids = (const int*)  d_in[0];
    const float* emb = (const float*)d_in[1];
    const float* W_f = (const float*)d_in[2];
    const float* U_f = (const float*)d_in[3];
    const float* b_f = (const float*)d_in[4];
    const float* W_b = (const float*)d_in[5];
    const float* U_b = (const float*)d_in[6];
    const float* b_b = (const float*)d_in[7];
    const float* W_k = (const float*)d_in[8];
    const float* b_k = (const float*)d_in[9];
    const float* W_q = (const float*)d_in[10];
    const float* b_q = (const float*)d_in[11];
    const float* W_e = (const float*)d_in[12];
    const float* b_e = (const float*)d_in[13];

    float* ws   = (float*)d_ws;
    // workspace layout (floats):
    //   x    : [0, 2'560'000)                 (B*S*E)
    //   mask : [2'560'000, 2'662'400)         (B*S)
    //   out  : [2'662'400, 15'769'600)        (B*S*2H)
    //   hT   : [15'769'600, 15'802'368)       (B*H)
    float* x    = ws;
    float* mask = ws + 2560000;
    float* out  = ws + 2662400;
    float* hT   = ws + 15769600;

    emb_mean_kernel<<<(BATCH * SEQ) / 8, 256, 0, stream>>>(ids, emb, x, mask);
    gru_kernel<<<1024, 384, 0, stream>>>(x, mask, W_f, U_f, b_f,
                                         W_b, U_b, b_b, out, hT);
    attn_kernel<<<BATCH, 256, 0, stream>>>(out, mask, hT, W_k, b_k,
                                           W_q, b_q, W_e, b_e, (float*)d_out);
}

// Round 6
// 430.105 us; speedup vs baseline: 1.1435x; 1.1435x over previous
//
#include <hip/hip_runtime.h>
#include <math.h>

#define BATCH 512
#define SEQ   200
#define TOK   10
#define EMB   25
#define XPAD  28    // xs row stride (floats): 112 B, 16B-aligned rows
#define HID   64
#define G3    192   // 3*HID
#define ATILE 8     // attn phase-1 s-tile

__device__ __forceinline__ float fast_sigmoid(float t) {
    float e = __expf(-t);
    return __builtin_amdgcn_rcpf(1.f + e);
}
__device__ __forceinline__ float fast_tanh(float t) {
    float e2 = __expf(2.f * t);
    return 1.f - 2.f * __builtin_amdgcn_rcpf(e2 + 1.f);
}

// Barrier that orders LDS producer->consumer WITHOUT draining vmcnt:
// writer-side ds ops complete (lgkmcnt(0)), then s_barrier. The global
// out-store stays fire-and-forget (no vmcnt(0) on the critical path).
#define LDS_BARRIER() do {                                   \
    asm volatile("s_waitcnt lgkmcnt(0)" ::: "memory");       \
    __builtin_amdgcn_s_barrier();                            \
    asm volatile("" ::: "memory");                           \
} while (0)

// ---------------------------------------------------------------------------
// Kernel 1: masked-mean embedding bag + step mask (unchanged)
// ---------------------------------------------------------------------------
__global__ __launch_bounds__(256) void emb_mean_kernel(
    const int* __restrict__ ids_g, const float* __restrict__ emb,
    float* __restrict__ x, float* __restrict__ mask)
{
    int grp  = blockIdx.x * 8 + (threadIdx.x >> 5);
    int lane = threadIdx.x & 31;
    if (grp >= BATCH * SEQ) return;
    const int* ids = ids_g + (size_t)grp * TOK;
    float acc = 0.f;
    int cnt = 0;
    #pragma unroll
    for (int t = 0; t < TOK; t++) {
        int id = ids[t];
        if (id != 0) {
            cnt++;
            if (lane < EMB) acc += emb[(size_t)id * EMB + lane];
        }
    }
    if (lane < EMB)
        x[(size_t)grp * EMB + lane] = cnt ? acc / (float)cnt : 0.f;
    if (lane == 0)
        mask[grp] = (ids[0] != 0) ? 1.f : 0.f;
}

// ---------------------------------------------------------------------------
// Kernel 2: GRU scan — exact round-2 configuration (best measured: 205 us).
// Allocator law (5 rounds of evidence): multi-wave blocks get a ~64-reg
// budget regardless of launch_bounds/waves_per_eu; demand beyond it is
// re-sunk into the loop (no pins) or scratch-spilled (pins). This config
// (3-wave gate-split, named scalars, no pins) is the family optimum.
// ---------------------------------------------------------------------------

#define U_LIST(M) \
  M(0)  M(1)  M(2)  M(3)  M(4)  M(5)  M(6)  M(7)  \
  M(8)  M(9)  M(10) M(11) M(12) M(13) M(14) M(15) \
  M(16) M(17) M(18) M(19) M(20) M(21) M(22) M(23) \
  M(24) M(25) M(26) M(27) M(28) M(29) M(30) M(31) \
  M(32) M(33) M(34) M(35) M(36) M(37) M(38) M(39) \
  M(40) M(41) M(42) M(43) M(44) M(45) M(46) M(47) \
  M(48) M(49) M(50) M(51) M(52) M(53) M(54) M(55) \
  M(56) M(57) M(58) M(59) M(60) M(61) M(62) M(63)

#define W_LIST(M) \
  M(0)  M(1)  M(2)  M(3)  M(4)  M(5)  M(6)  M(7)  \
  M(8)  M(9)  M(10) M(11) M(12) M(13) M(14) M(15) \
  M(16) M(17) M(18) M(19) M(20) M(21) M(22) M(23) M(24)

#define DECL_U(i) const float u##i = U[(i) * G3 + col];
#define DECL_W(i) const float w##i = W[(i) * G3 + col];

// one float4 broadcast read of hs, 4 fmas
#define REC4(q, i0, i1, i2, i3) {                 \
    const float4 hv = hs4[q];                     \
    a0 = fmaf(hv.x, u##i0, a0);                   \
    a1 = fmaf(hv.y, u##i1, a1);                   \
    a2 = fmaf(hv.z, u##i2, a2);                   \
    a3 = fmaf(hv.w, u##i3, a3); }

#define X4(q, i0, i1, i2, i3) {                   \
    const float4 xv = xr4[q];                     \
    p0 = fmaf(xv.x, w##i0, p0);                   \
    p1 = fmaf(xv.y, w##i1, p1);                   \
    p2 = fmaf(xv.z, w##i2, p2);                   \
    p3 = fmaf(xv.w, w##i3, p3); }

// x-projection of row XR (float* into xs, stride-XPAD row, 16B aligned)
#define XPROJ(P, XR) do {                                         \
    const float4* xr4 = (const float4*)(XR);                      \
    float p0 = bx, p1 = 0.f, p2 = 0.f, p3 = 0.f;                  \
    X4(0, 0, 1, 2, 3)   X4(1, 4, 5, 6, 7)   X4(2, 8, 9, 10, 11)  \
    X4(3, 12, 13, 14, 15) X4(4, 16, 17, 18, 19) X4(5, 20, 21, 22, 23) \
    p0 = fmaf((XR)[24], w24, p0);                                 \
    P = (p0 + p1) + (p2 + p3);                                    \
} while (0)

__global__ __launch_bounds__(192, 3) void gru_kernel(
    const float* __restrict__ xg, const float* __restrict__ maskg,
    const float* __restrict__ W_f, const float* __restrict__ U_f, const float* __restrict__ b_f,
    const float* __restrict__ W_b, const float* __restrict__ U_b, const float* __restrict__ b_b,
    float* __restrict__ outg, float* __restrict__ hT)
{
    const int bidx = blockIdx.x;
    const int dir  = bidx >> 9;        // 0 = forward, 1 = backward
    const int b    = bidx & 511;
    const int tid  = threadIdx.x;
    const int w    = tid >> 6;         // gate index: 0=z, 1=r, 2=h
    const int j    = tid & 63;         // hidden column

    const float* W    = dir ? W_b : W_f;
    const float* U    = dir ? U_b : U_f;
    const float* bias = dir ? b_b : b_f;

    const int col = w * HID + j;

    // per-lane weight column for THIS gate, as named scalars
    U_LIST(DECL_U)
    W_LIST(DECL_W)
    const float bx = bias[col];        // input-projection bias
    const float br = bias[G3 + col];   // recurrent bias

    __shared__ __align__(16) float xs[SEQ * XPAD];   // 22.4 KB, padded rows
    __shared__ float ms[SEQ];
    __shared__ __align__(16) float hs[HID];
    __shared__ float zs[HID];
    __shared__ float rs[HID];

    // cooperative staging (coalesced global reads, padded LDS rows)
    {
        for (int i = tid; i < SEQ * EMB; i += 192) {
            int s = i / EMB;
            int e = i - s * EMB;
            xs[s * XPAD + e] = xg[(size_t)b * (SEQ * EMB) + i];
        }
        for (int i = tid; i < SEQ; i += 192) ms[i] = maskg[(size_t)b * SEQ + i];
        if (tid < HID) hs[tid] = 0.f;
    }
    __syncthreads();   // staging barrier (vmcnt drain fine, once)

    const float4* hs4 = (const float4*)hs;
    float h = 0.f;     // running hidden state, live only in wave 2
    float* obase = outg + (size_t)b * SEQ * (2 * HID) + dir * HID + j;

    // software-pipelined x-projection for step 0
    float p;
    {
        const int s0 = dir ? (SEQ - 1) : 0;
        XPROJ(p, xs + s0 * XPAD);
    }

    for (int step = 0; step < SEQ; step++) {
        const int s = dir ? (SEQ - 1 - step) : step;

        // recurrent dot: a = br + hs . u   (broadcast b128 reads, reg weights)
        float a0 = br, a1 = 0.f, a2 = 0.f, a3 = 0.f;
        REC4(0,  0,  1,  2,  3)   REC4(1,  4,  5,  6,  7)
        REC4(2,  8,  9, 10, 11)   REC4(3, 12, 13, 14, 15)
        REC4(4, 16, 17, 18, 19)   REC4(5, 20, 21, 22, 23)
        REC4(6, 24, 25, 26, 27)   REC4(7, 28, 29, 30, 31)
        REC4(8, 32, 33, 34, 35)   REC4(9, 36, 37, 38, 39)
        REC4(10, 40, 41, 42, 43)  REC4(11, 44, 45, 46, 47)
        REC4(12, 48, 49, 50, 51)  REC4(13, 52, 53, 54, 55)
        REC4(14, 56, 57, 58, 59)  REC4(15, 60, 61, 62, 63)
        const float a = (a0 + a1) + (a2 + a3);

        if (w == 0)      zs[j] = fast_sigmoid(p + a);
        else if (w == 1) rs[j] = fast_sigmoid(p + a);

        LDS_BARRIER();   // A: zs/rs visible to wave 2

        if (w == 2) {
            float r  = rs[j];
            float z  = zs[j];
            float hh = fast_tanh(p + r * a);        // p = xh-part, a = rec-part
            float hn = z * h + (1.f - z) * hh;
            hn = (ms[s] != 0.f) ? hn : h;
            h = hn;
            hs[j] = hn;
            obase[(size_t)s * (2 * HID)] = hn;      // fire-and-forget
        }

        // x-projection for the NEXT step (h-independent): overlaps wave-2's
        // combine latency and waves 0/1's barrier wait.
        {
            const int sn  = dir ? (SEQ - 2 - step) : (step + 1);
            const int snc = (step + 1 < SEQ) ? sn : s;   // clamp (unused on last iter)
            XPROJ(p, xs + snc * XPAD);
        }

        LDS_BARRIER();   // B: new hs visible to all waves
    }
    if (w == 2 && dir == 0) hT[(size_t)b * HID + j] = h;
}

// ---------------------------------------------------------------------------
// Kernel 3: attention pooling, v2. One block (256 thr = 4 waves) per batch.
// Old phase 1 read Wks per-lane from LDS: 128 ds_read_b32 per s-iter ->
// 51,200 ds_reads/CU x ~5.8cy ~= 124 us of DS-pipe serialization (the
// hidden half of the runtime). v2 applies the gru pattern: W_k slice in
// REGISTERS (wave w owns i-rows [32w,32w+32), lane = col j; 32 named
// scalars, ~50 regs total -> fits the 64-reg tier, no allocator fight),
// uniform float4 reads of the out-row, partials combined via a small LDS
// tile. Phase 3 now uses all 4 waves (s-split), float2 per lane, LDS
// partial reduce.
// ---------------------------------------------------------------------------

#define WK_LIST(M) \
  M(0)  M(1)  M(2)  M(3)  M(4)  M(5)  M(6)  M(7)  \
  M(8)  M(9)  M(10) M(11) M(12) M(13) M(14) M(15) \
  M(16) M(17) M(18) M(19) M(20) M(21) M(22) M(23) \
  M(24) M(25) M(26) M(27) M(28) M(29) M(30) M(31)

#define DECL_WK(t) const float wk##t = W_k[(size_t)(32 * wave + (t)) * HID + lane];

#define KF4(q, t0, t1, t2, t3) {                  \
    const float4 ov = o4[q];                      \
    acc0 = fmaf(ov.x, wk##t0, acc0);              \
    acc1 = fmaf(ov.y, wk##t1, acc1);              \
    acc0 = fmaf(ov.z, wk##t2, acc0);              \
    acc1 = fmaf(ov.w, wk##t3, acc1); }

__global__ __launch_bounds__(256) void attn_kernel(
    const float* __restrict__ outg, const float* __restrict__ maskg,
    const float* __restrict__ hT,
    const float* __restrict__ W_k, const float* __restrict__ b_k,
    const float* __restrict__ W_q, const float* __restrict__ b_q,
    const float* __restrict__ W_e, const float* __restrict__ b_e,
    float* __restrict__ ctx)
{
    const int b    = blockIdx.x;
    const int tid  = threadIdx.x;
    const int wave = tid >> 6;
    const int lane = tid & 63;

    __shared__ float qs[HID];
    __shared__ float es[SEQ];
    __shared__ __align__(16) float kp[ATILE][4][HID];   // 8 KB partial keys
    __shared__ __align__(16) float psum[4][2 * HID];    // 2 KB phase-3 partials

    // per-lane W_k slice (coalesced loads; ~50 regs total, under the tier)
    WK_LIST(DECL_WK)

    const float bkj = b_k[lane];
    const float wej = W_e[lane];
    const float be  = b_e[0];

    // q[j] = b_q[j] + hT[b,:] . W_q[:,j]
    if (tid < HID) {
        float q = b_q[tid];
        const float* hrow = hT + (size_t)b * HID;
        #pragma unroll 8
        for (int i = 0; i < HID; i++) q = fmaf(hrow[i], W_q[i * HID + tid], q);
        qs[tid] = q;
    }
    __syncthreads();
    const float qj = qs[lane];

    // phase 1: scores e[s], tiled by ATILE
    for (int s0 = 0; s0 < SEQ; s0 += ATILE) {
        #pragma unroll 2
        for (int t = 0; t < ATILE; t++) {
            const int s = s0 + t;
            const float4* o4 = (const float4*)(outg +
                ((size_t)b * SEQ + s) * (2 * HID) + 32 * wave);
            float acc0 = 0.f, acc1 = 0.f;
            KF4(0,  0,  1,  2,  3)  KF4(1,  4,  5,  6,  7)
            KF4(2,  8,  9, 10, 11)  KF4(3, 12, 13, 14, 15)
            KF4(4, 16, 17, 18, 19)  KF4(5, 20, 21, 22, 23)
            KF4(6, 24, 25, 26, 27)  KF4(7, 28, 29, 30, 31)
            kp[t][wave][lane] = acc0 + acc1;
        }
        __syncthreads();
        #pragma unroll
        for (int t = wave; t < ATILE; t += 4) {
            const int s = s0 + t;
            float k = (kp[t][0][lane] + kp[t][1][lane]) +
                      (kp[t][2][lane] + kp[t][3][lane]);
            float v = tanhf(k + bkj + qj) * wej;
            #pragma unroll
            for (int off = 32; off > 0; off >>= 1) v += __shfl_xor(v, off);
            if (lane == 0) {
                float pen = (maskg[(size_t)b * SEQ + s] != 0.f) ? 0.f : -1e9f;
                es[s] = v + be + pen;
            }
        }
        __syncthreads();
    }

    // phase 2: softmax over the 200 scores (single wave)
    if (tid < 64) {
        float mx = -1e30f;
        for (int s2 = tid; s2 < SEQ; s2 += 64) mx = fmaxf(mx, es[s2]);
        #pragma unroll
        for (int off = 32; off > 0; off >>= 1) mx = fmaxf(mx, __shfl_xor(mx, off));
        float sum = 0.f;
        for (int s2 = tid; s2 < SEQ; s2 += 64) {
            float w = expf(es[s2] - mx);
            es[s2] = w;
            sum += w;
        }
        #pragma unroll
        for (int off = 32; off > 0; off >>= 1) sum += __shfl_xor(sum, off);
        float inv = 1.f / sum;
        for (int s2 = tid; s2 < SEQ; s2 += 64) es[s2] *= inv;
    }
    __syncthreads();

    // phase 3: context[j] = sum_s w[s] * out[b,s,j] — all 4 waves, s-split
    {
        float a0 = 0.f, a1 = 0.f;
        #pragma unroll 2
        for (int s2 = wave; s2 < SEQ; s2 += 4) {
            const float2 v = *(const float2*)(outg +
                ((size_t)b * SEQ + s2) * (2 * HID) + lane * 2);
            const float wsc = es[s2];
            a0 = fmaf(wsc, v.x, a0);
            a1 = fmaf(wsc, v.y, a1);
        }
        psum[wave][2 * lane]     = a0;
        psum[wave][2 * lane + 1] = a1;
    }
    __syncthreads();
    if (tid < 2 * HID) {
        ctx[(size_t)b * (2 * HID) + tid] =
            (psum[0][tid] + psum[1][tid]) + (psum[2][tid] + psum[3][tid]);
    }
}

// ---------------------------------------------------------------------------
extern "C" void kernel_launch(void* const* d_in, const int* in_sizes, int n_in,
                              void* d_out, int out_size, void* d_ws, size_t ws_size,
                              hipStream_t stream) {
    const int*   ids = (const int*)  d_in[0];
    const float* emb = (const float*)d_in[1];
    const float* W_f = (const float*)d_in[2];
    const float* U_f = (const float*)d_in[3];
    const float* b_f = (const float*)d_in[4];
    const float* W_b = (const float*)d_in[5];
    const float* U_b = (const float*)d_in[6];
    const float* b_b = (const float*)d_in[7];
    const float* W_k = (const float*)d_in[8];
    const float* b_k = (const float*)d_in[9];
    const float* W_q = (const float*)d_in[10];
    const float* b_q = (const float*)d_in[11];
    const float* W_e = (const float*)d_in[12];
    const float* b_e = (const float*)d_in[13];

    float* ws   = (float*)d_ws;
    // workspace layout (floats):
    //   x    : [0, 2'560'000)                 (B*S*E)
    //   mask : [2'560'000, 2'662'400)         (B*S)
    //   out  : [2'662'400, 15'769'600)        (B*S*2H)
    //   hT   : [15'769'600, 15'802'368)       (B*H)
    float* x    = ws;
    float* mask = ws + 2560000;
    float* out  = ws + 2662400;
    float* hT   = ws + 15769600;

    emb_mean_kernel<<<(BATCH * SEQ) / 8, 256, 0, stream>>>(ids, emb, x, mask);
    gru_kernel<<<1024, 192, 0, stream>>>(x, mask, W_f, U_f, b_f,
                                         W_b, U_b, b_b, out, hT);
    attn_kernel<<<BATCH, 256, 0, stream>>>(out, mask, hT, W_k, b_k,
                                           W_q, b_q, W_e, b_e, (float*)d_out);
}